// Round 1
// baseline (198.760 us; speedup 1.0000x reference)
//
#include <hip/hip_runtime.h>
#include <hip/hip_bf16.h>
#include <math.h>

// Problem: B=4, L=2048 (M = 8192 rows), D_MODEL = 768, N_STATE = 16.
// y[row,d] = x[row,d] * softplus((x@W1+b1)[row,d]) * dot(x@W2+b2, x@W3+b3)[row]
// (the dA*h0 term is identically zero; A is unused.)

#define M_ROWS 8192
#define DM 768
#define NS 16

typedef short bf16x8 __attribute__((ext_vector_type(8)));
typedef float f32x4 __attribute__((ext_vector_type(4)));

__device__ __forceinline__ unsigned short f2bf(float f) {
    union { float f; unsigned u; } v; v.f = f;
    unsigned r = v.u + 0x7FFF + ((v.u >> 16) & 1);   // round-to-nearest-even
    return (unsigned short)(r >> 16);
}

__device__ __forceinline__ void async16(const void* g, void* l) {
    __builtin_amdgcn_global_load_lds(
        (const __attribute__((address_space(1))) void*)g,
        (__attribute__((address_space(3))) void*)l,
        16, 0, 0);
}

// ---- kernel 1: x (fp32) -> xb (bf16), flat ------------------------------
__global__ __launch_bounds__(256) void convert_x_kernel(
    const float* __restrict__ x, unsigned short* __restrict__ xb)
{
    int i = blockIdx.x * 256 + threadIdx.x;          // one float4 per thread
    float4 v = ((const float4*)x)[i];
    ushort4 o;
    o.x = f2bf(v.x); o.y = f2bf(v.y); o.z = f2bf(v.z); o.w = f2bf(v.w);
    ((ushort4*)xb)[i] = o;
}

// ---- kernel 2: W1 [k][n] fp32 -> W1t [n][k] bf16 ------------------------
__global__ __launch_bounds__(256) void transpose_w1_kernel(
    const float* __restrict__ W1, unsigned short* __restrict__ W1t)
{
    __shared__ float tile[32][33];
    int n0 = blockIdx.x * 32, k0 = blockIdx.y * 32;
    int tx = threadIdx.x & 31, ty = threadIdx.x >> 5;   // 32 x 8
    #pragma unroll
    for (int i = 0; i < 4; ++i) {
        int k = ty + i * 8;
        tile[k][tx] = W1[(k0 + k) * DM + n0 + tx];
    }
    __syncthreads();
    #pragma unroll
    for (int i = 0; i < 4; ++i) {
        int n = ty + i * 8;
        W1t[(n0 + n) * DM + k0 + tx] = f2bf(tile[tx][n]);
    }
}

// ---- kernel 3: s[row] = dot(x@W2+b2, x@W3+b3) ---------------------------
// one wave per row; lane strides d by 64 (12 iters); butterfly reduce.
__global__ __launch_bounds__(256) void s_kernel(
    const float* __restrict__ x,
    const float* __restrict__ W2, const float* __restrict__ b2,
    const float* __restrict__ W3, const float* __restrict__ b3,
    float* __restrict__ s_out)
{
    int wave = threadIdx.x >> 6, lane = threadIdx.x & 63;
    int row = blockIdx.x * 4 + wave;
    const float* xr = x + row * DM;
    float aB[16], aC[16];
    #pragma unroll
    for (int n = 0; n < 16; ++n) { aB[n] = 0.f; aC[n] = 0.f; }
    #pragma unroll 4
    for (int it = 0; it < 12; ++it) {
        int d = lane + it * 64;
        float xv = xr[d];
        const float4* w2 = (const float4*)(W2 + d * NS);
        const float4* w3 = (const float4*)(W3 + d * NS);
        #pragma unroll
        for (int q = 0; q < 4; ++q) {
            float4 a = w2[q], c = w3[q];
            aB[q*4+0] += xv * a.x; aB[q*4+1] += xv * a.y;
            aB[q*4+2] += xv * a.z; aB[q*4+3] += xv * a.w;
            aC[q*4+0] += xv * c.x; aC[q*4+1] += xv * c.y;
            aC[q*4+2] += xv * c.z; aC[q*4+3] += xv * c.w;
        }
    }
    #pragma unroll
    for (int n = 0; n < 16; ++n) {
        #pragma unroll
        for (int off = 32; off; off >>= 1) {
            aB[n] += __shfl_xor(aB[n], off, 64);
            aC[n] += __shfl_xor(aC[n], off, 64);
        }
    }
    if (lane == 0) {
        float s = 0.f;
        #pragma unroll
        for (int n = 0; n < 16; ++n)
            s += (aB[n] + b2[n]) * (aC[n] + b3[n]);
        s_out[row] = s;
    }
}

// ---- kernel 4: fused bf16 MFMA GEMM + softplus/scale epilogue -----------
// C[m,n] = sum_k xb[m,k] * W1t[n,k];  y = x * softplus(C + b1) * s[m]
// 128x128 block tile, BK=32, 4 waves (2x2), each wave 4x4 of 16x16x32 MFMA.
__global__ __launch_bounds__(256) void gemm_fused_kernel(
    const unsigned short* __restrict__ xb,    // [8192][768] bf16
    const unsigned short* __restrict__ w1t,   // [768][768] bf16, n-major
    const float* __restrict__ x,              // fp32 for epilogue
    const float* __restrict__ b1,
    const float* __restrict__ s_arr,
    float* __restrict__ y)
{
    __shared__ unsigned short Al[128 * 32];
    __shared__ unsigned short Bl[128 * 32];
    const int m0 = blockIdx.y * 128;
    const int n0 = blockIdx.x * 128;
    const int tid  = threadIdx.x;
    const int lane = tid & 63;
    const int wave = tid >> 6;
    const int wm = wave >> 1, wn = wave & 1;
    const int l15 = lane & 15, quad = lane >> 4;

    f32x4 acc[4][4];
    #pragma unroll
    for (int i = 0; i < 4; ++i)
        #pragma unroll
        for (int j = 0; j < 4; ++j)
            acc[i][j] = (f32x4){0.f, 0.f, 0.f, 0.f};

    for (int k0 = 0; k0 < DM; k0 += 32) {
        // stage 128x32 bf16 tiles of A and B via async global->LDS, 16B/lane.
        // chunk c in [0,512): LDS offset c*16B; row = c>>2, col8 = (c&3)*8.
        // lds dest for lane l is (wave-uniform base) + l*16 -- layout matches.
        #pragma unroll
        for (int i = 0; i < 2; ++i) {
            int c = tid + i * 256;
            int r = c >> 2, c8 = (c & 3) * 8;
            async16(xb  + (m0 + r) * DM + k0 + c8, Al + c * 8);
            async16(w1t + (n0 + r) * DM + k0 + c8, Bl + c * 8);
        }
        __syncthreads();   // drains vmcnt before LDS reads

        bf16x8 af[4], bf[4];
        const int kq = quad * 8;
        #pragma unroll
        for (int i = 0; i < 4; ++i) {
            af[i] = *(const bf16x8*)(Al + (wm * 64 + i * 16 + l15) * 32 + kq);
            bf[i] = *(const bf16x8*)(Bl + (wn * 64 + i * 16 + l15) * 32 + kq);
        }
        #pragma unroll
        for (int i = 0; i < 4; ++i)
            #pragma unroll
            for (int j = 0; j < 4; ++j)
                acc[i][j] = __builtin_amdgcn_mfma_f32_16x16x32_bf16(
                    af[i], bf[j], acc[i][j], 0, 0, 0);
        __syncthreads();   // before restaging
    }

    // epilogue: C/D layout col = lane&15, row = quad*4 + reg
    #pragma unroll
    for (int i = 0; i < 4; ++i) {
        #pragma unroll
        for (int j = 0; j < 4; ++j) {
            int gcol = n0 + wn * 64 + j * 16 + l15;
            float bias = b1[gcol];
            #pragma unroll
            for (int r = 0; r < 4; ++r) {
                int grow = m0 + wm * 64 + i * 16 + quad * 4 + r;
                float v = acc[i][j][r] + bias;
                float sp = (v > 20.f) ? v : log1pf(__expf(v));
                y[grow * DM + gcol] = x[grow * DM + gcol] * sp * s_arr[grow];
            }
        }
    }
}

extern "C" void kernel_launch(void* const* d_in, const int* in_sizes, int n_in,
                              void* d_out, int out_size, void* d_ws, size_t ws_size,
                              hipStream_t stream) {
    const float* x  = (const float*)d_in[0];
    const float* W1 = (const float*)d_in[1];
    const float* b1 = (const float*)d_in[2];
    const float* W2 = (const float*)d_in[3];
    const float* b2 = (const float*)d_in[4];
    const float* W3 = (const float*)d_in[5];
    const float* b3 = (const float*)d_in[6];
    // d_in[7] = A : unused (multiplied by h0 == 0 in the reference)
    float* y = (float*)d_out;

    // workspace layout
    unsigned short* xb  = (unsigned short*)d_ws;                       // 12,582,912 B
    unsigned short* w1t = (unsigned short*)((char*)d_ws + 12582912);   //  1,179,648 B
    float*          sarr = (float*)((char*)d_ws + 13762560);           //     32,768 B

    convert_x_kernel<<<M_ROWS * DM / 4 / 256, 256, 0, stream>>>(x, xb);
    transpose_w1_kernel<<<dim3(DM / 32, DM / 32), 256, 0, stream>>>(W1, w1t);
    s_kernel<<<M_ROWS / 4, 256, 0, stream>>>(x, W2, b2, W3, b3, sarr);
    gemm_fused_kernel<<<dim3(DM / 128, M_ROWS / 128), 256, 0, stream>>>(
        xb, w1t, x, b1, sarr, y);
}

// Round 2
// 175.180 us; speedup vs baseline: 1.1346x; 1.1346x over previous
//
#include <hip/hip_runtime.h>
#include <hip/hip_bf16.h>
#include <math.h>

// Problem: B=4, L=2048 (M = 8192 rows), D_MODEL = 768, N_STATE = 16.
// y[row,d] = x[row,d] * softplus((x@W1+b1)[row,d]) * dot(x@W2+b2, x@W3+b3)[row]
// (dA*h0 term is identically zero; A unused.)

#define M_ROWS 8192
#define DM 768
#define NS 16

typedef short bf16x8 __attribute__((ext_vector_type(8)));
typedef float f32x4 __attribute__((ext_vector_type(4)));

__device__ __forceinline__ unsigned short f2bf(float f) {
    union { float f; unsigned u; } v; v.f = f;
    unsigned r = v.u + 0x7FFF + ((v.u >> 16) & 1);   // RNE
    return (unsigned short)(r >> 16);
}
__device__ __forceinline__ float bf2f(unsigned short h) {
    union { unsigned u; float f; } v; v.u = ((unsigned)h) << 16; return v.f;
}
__device__ __forceinline__ void async16(const void* g, void* l) {
    __builtin_amdgcn_global_load_lds(
        (const __attribute__((address_space(1))) void*)g,
        (__attribute__((address_space(3))) void*)l,
        16, 0, 0);
}

// ---- kernel 1: block-specialized prep -----------------------------------
// blocks [0,2048):    per wave, one row: convert x->xb (bf16) AND
//                     s[row] = dot(x@W2+b2, x@W3+b3)  (shuffle-reduced)
// blocks [2048,2624): W1 [k][n] fp32 -> w1t [n][k] bf16 (32x32 LDS tiles)
__global__ __launch_bounds__(256) void prep_kernel(
    const float* __restrict__ x,
    const float* __restrict__ W1,
    const float* __restrict__ W2, const float* __restrict__ b2,
    const float* __restrict__ W3, const float* __restrict__ b3,
    unsigned short* __restrict__ xb,
    unsigned short* __restrict__ w1t,
    float* __restrict__ s_out)
{
    __shared__ float tile[32][33];
    const int bid = blockIdx.x;
    if (bid < 2048) {
        const int wave = threadIdx.x >> 6, lane = threadIdx.x & 63;
        const int row = bid * 4 + wave;
        const float* xr = x + row * DM;
        unsigned short* xbr = xb + row * DM;
        float aB[16], aC[16];
        #pragma unroll
        for (int n = 0; n < 16; ++n) { aB[n] = 0.f; aC[n] = 0.f; }
        #pragma unroll 4
        for (int it = 0; it < 12; ++it) {
            int d = it * 64 + lane;
            float xv = xr[d];
            xbr[d] = f2bf(xv);
            const float4* w2 = (const float4*)(W2 + d * NS);
            const float4* w3 = (const float4*)(W3 + d * NS);
            #pragma unroll
            for (int q = 0; q < 4; ++q) {
                float4 a = w2[q], c = w3[q];
                aB[q*4+0] += xv * a.x; aB[q*4+1] += xv * a.y;
                aB[q*4+2] += xv * a.z; aB[q*4+3] += xv * a.w;
                aC[q*4+0] += xv * c.x; aC[q*4+1] += xv * c.y;
                aC[q*4+2] += xv * c.z; aC[q*4+3] += xv * c.w;
            }
        }
        #pragma unroll
        for (int n = 0; n < 16; ++n) {
            #pragma unroll
            for (int off = 32; off; off >>= 1) {
                aB[n] += __shfl_xor(aB[n], off, 64);
                aC[n] += __shfl_xor(aC[n], off, 64);
            }
        }
        if (lane == 0) {
            float s = 0.f;
            #pragma unroll
            for (int n = 0; n < 16; ++n)
                s += (aB[n] + b2[n]) * (aC[n] + b3[n]);
            s_out[row] = s;
        }
    } else {
        const int b2i = bid - 2048;               // 0..575
        const int n0 = (b2i % 24) * 32, k0 = (b2i / 24) * 32;
        const int tx = threadIdx.x & 31, ty = threadIdx.x >> 5;  // 32 x 8
        #pragma unroll
        for (int i = 0; i < 4; ++i) {
            int k = ty + i * 8;
            tile[k][tx] = W1[(k0 + k) * DM + n0 + tx];
        }
        __syncthreads();
        #pragma unroll
        for (int i = 0; i < 4; ++i) {
            int n = ty + i * 8;
            w1t[(n0 + n) * DM + k0 + tx] = f2bf(tile[tx][n]);
        }
    }
}

// ---- kernel 2: fused bf16 MFMA GEMM + softplus/scale epilogue -----------
// 64x64 block tile, BK=64, 4 waves (2x2), wave = 2x2 of 16x16x32 MFMA.
// grid = (768/64=12, 8192/64=128) = 1536 blocks -> ~6 blocks/CU.
// LDS rows are 128 B; XOR-swizzle 16B chunks (j ^ (row&7)) applied on the
// global source of global_load_lds and mirrored in ds_read addressing to
// kill the 16-way bank conflicts a 128 B stride would cause.
__global__ __launch_bounds__(256) void gemm_fused_kernel(
    const unsigned short* __restrict__ xb,    // [8192][768] bf16
    const unsigned short* __restrict__ w1t,   // [768][768] bf16, n-major
    const float* __restrict__ b1,
    const float* __restrict__ s_arr,
    float* __restrict__ y)
{
    __shared__ unsigned short Al[64 * 64];
    __shared__ unsigned short Bl[64 * 64];
    const int m0 = blockIdx.y * 64;
    const int n0 = blockIdx.x * 64;
    const int tid  = threadIdx.x;
    const int lane = tid & 63;
    const int wave = tid >> 6;
    const int wm = wave >> 1, wn = wave & 1;
    const int l15 = lane & 15, quad = lane >> 4;

    f32x4 acc[2][2];
    #pragma unroll
    for (int i = 0; i < 2; ++i)
        #pragma unroll
        for (int j = 0; j < 2; ++j)
            acc[i][j] = (f32x4){0.f, 0.f, 0.f, 0.f};

    for (int k0 = 0; k0 < DM; k0 += 64) {
        // stage 64x64 bf16 tiles: 8 KB = 512 chunks of 16 B; 2 chunks/thread.
        #pragma unroll
        for (int i = 0; i < 2; ++i) {
            int c = tid + i * 256;        // lds chunk, lane-contiguous
            int r = c >> 3;               // tile row
            int jl = c & 7;               // lds chunk-in-row
            int jg = jl ^ (r & 7);        // swizzled global chunk
            async16(xb  + (m0 + r) * DM + k0 + jg * 8, Al + c * 8);
            async16(w1t + (n0 + r) * DM + k0 + jg * 8, Bl + c * 8);
        }
        __syncthreads();

        bf16x8 af[2][2], bq[2][2];
        #pragma unroll
        for (int i = 0; i < 2; ++i) {
            #pragma unroll
            for (int kk = 0; kk < 2; ++kk) {
                int rr = wm * 32 + i * 16 + l15;
                int ja = (kk * 4 + quad) ^ (rr & 7);
                af[i][kk] = *(const bf16x8*)(Al + rr * 64 + ja * 8);
                int rb = wn * 32 + i * 16 + l15;
                int jb = (kk * 4 + quad) ^ (rb & 7);
                bq[i][kk] = *(const bf16x8*)(Bl + rb * 64 + jb * 8);
            }
        }
        #pragma unroll
        for (int kk = 0; kk < 2; ++kk)
            #pragma unroll
            for (int i = 0; i < 2; ++i)
                #pragma unroll
                for (int j = 0; j < 2; ++j)
                    acc[i][j] = __builtin_amdgcn_mfma_f32_16x16x32_bf16(
                        af[i][kk], bq[j][kk], acc[i][j], 0, 0, 0);
        __syncthreads();
    }

    // epilogue: C/D layout col = lane&15, row = quad*4 + reg
    #pragma unroll
    for (int i = 0; i < 2; ++i) {
        #pragma unroll
        for (int j = 0; j < 2; ++j) {
            int gcol = n0 + wn * 32 + j * 16 + l15;
            float bias = b1[gcol];
            #pragma unroll
            for (int r = 0; r < 4; ++r) {
                int grow = m0 + wm * 32 + i * 16 + quad * 4 + r;
                float v = acc[i][j][r] + bias;
                float sp = (v > 20.f) ? v : log1pf(__expf(v));
                float xv = bf2f(xb[grow * DM + gcol]);
                y[grow * DM + gcol] = xv * sp * s_arr[grow];
            }
        }
    }
}

extern "C" void kernel_launch(void* const* d_in, const int* in_sizes, int n_in,
                              void* d_out, int out_size, void* d_ws, size_t ws_size,
                              hipStream_t stream) {
    const float* x  = (const float*)d_in[0];
    const float* W1 = (const float*)d_in[1];
    const float* b1 = (const float*)d_in[2];
    const float* W2 = (const float*)d_in[3];
    const float* b2 = (const float*)d_in[4];
    const float* W3 = (const float*)d_in[5];
    const float* b3 = (const float*)d_in[6];
    // d_in[7] = A : unused (multiplied by h0 == 0 in the reference)
    float* y = (float*)d_out;

    unsigned short* xb   = (unsigned short*)d_ws;                      // 12,582,912 B
    unsigned short* w1t  = (unsigned short*)((char*)d_ws + 12582912);  //  1,179,648 B
    float*          sarr = (float*)((char*)d_ws + 13762560);           //     32,768 B

    prep_kernel<<<2048 + 576, 256, 0, stream>>>(x, W1, W2, b2, W3, b3,
                                                xb, w1t, sarr);
    gemm_fused_kernel<<<dim3(DM / 64, M_ROWS / 64), 256, 0, stream>>>(
        xb, w1t, b1, sarr, y);
}